// Round 2
// baseline (16025.061 us; speedup 1.0000x reference)
//
#include <hip/hip_runtime.h>
#include <math.h>

#define B_SZ 1024
#define T_SZ 512
#define C_CH 65
#define HID 160
#define G3  480   // 3*HID
#define OUTD 32

// ---------------- phase 0: zero any-flags ----------------
__global__ void k_zero(unsigned* __restrict__ anyv) {
  int i = blockIdx.x * blockDim.x + threadIdx.x;
  if (i < T_SZ) anyv[i] = 0u;
}

// ---------------- phase 1: obs[b][t] + any_obs[t] ----------------
__global__ __launch_bounds__(256) void k_obs(const float* __restrict__ X,
                                             unsigned char* __restrict__ obs,
                                             unsigned* __restrict__ anyv) {
  const int b = blockIdx.x;
  const float* Xb = X + (size_t)b * T_SZ * C_CH;
  for (int t = threadIdx.x; t < T_SZ; t += blockDim.x) {
    const float* cur = Xb + t * C_CH;
    const float* prv = cur - C_CH;
    float m = -1e30f;
    if (t == 0) {
      #pragma unroll
      for (int c = 1; c <= 32; ++c) m = fmaxf(m, cur[c]);
    } else {
      #pragma unroll
      for (int c = 1; c <= 32; ++c) m = fmaxf(m, cur[c] - prv[c]);
    }
    unsigned char o = (m > 0.5f) ? (unsigned char)1 : (unsigned char)0;
    obs[(size_t)b * T_SZ + t] = o;
    if (o) atomicOr(&anyv[t], 1u);
  }
}

__device__ __forceinline__ float sigm_f(float v) {
  return 1.f / (1.f + __expf(-v));
}
__device__ __forceinline__ float tanh_f(float v) {
  float a = fabsf(v);
  float e = __expf(-2.f * a);
  float m = (1.f - e) / (1.f + e);
  return copysignf(m, v);
}

// ---------------- phase 2: recurrence, one block (1024 thr) per element ----
// Row split: thread j (j<480) owns wih[j][0:32) + whh[j][0:64)   (96 w)
//            thread 512+j     owns whh[j][64:160)                (96 w)
__global__ __launch_bounds__(1024, 4) void k_scan(
    const float* __restrict__ times, const float* __restrict__ X,
    const int* __restrict__ fidx,
    const float* __restrict__ w_ih, const float* __restrict__ w_hh,
    const float* __restrict__ b_ih, const float* __restrict__ b_hh,
    const float* __restrict__ lin_w, const float* __restrict__ lin_b,
    const unsigned char* __restrict__ obs, const unsigned* __restrict__ anyv,
    float* __restrict__ out)
{
  const int b = blockIdx.x;
  const int tid = threadIdx.x;
  const int fi = fidx[b];
  const float* Xb = X + (size_t)b * T_SZ * C_CH;

  __shared__ __align__(16) float hf[HID];      // hidden state
  __shared__ float2 plo[G3];                   // (gi_partial, gh_lo_partial)
  __shared__ float  phi[G3];                   // gh_hi_partial
  __shared__ float  times_lds[T_SZ];
  __shared__ __align__(16) float xs[2][32];    // dbuf x-piece (ch 33..64)
  __shared__ float  xd0f[2];                   // channel-0 (time delta chan)
  __shared__ int    flagA[2], flagO[2];

  if (tid < T_SZ) times_lds[tid] = times[tid];
  if (tid < HID)  hf[tid] = 0.f;

  const bool isLo = (tid < G3);
  const bool isHi = (tid >= 512 && tid < 512 + G3);
  const int  row  = isLo ? tid : (tid - 512);

  float4 w4[24];                               // 96 weight floats in VGPRs
  float bi = 0.f, bhlo = 0.f;
  if (isLo) {
    const float4* wi = (const float4*)(w_ih + row * 32);
    #pragma unroll
    for (int q = 0; q < 8; ++q) w4[q] = wi[q];
    const float4* wh = (const float4*)(w_hh + (size_t)row * HID);
    #pragma unroll
    for (int q = 0; q < 16; ++q) w4[8 + q] = wh[q];
    bi = b_ih[row];
    bhlo = b_hh[row];
  } else if (isHi) {
    const float4* wh = (const float4*)(w_hh + (size_t)row * HID + 64);
    #pragma unroll
    for (int q = 0; q < 24; ++q) w4[q] = wh[q];
  }

  // stage step 0 into parity 0
  if (tid < 32)       xs[0][tid] = Xb[33 + tid];
  else if (tid == 32) xd0f[0] = Xb[0];
  else if (tid == 33) flagA[0] = (int)anyv[0];
  else if (tid == 34) flagO[0] = (int)obs[(size_t)b * T_SZ];
  float dt = 0.f;
  __syncthreads();

  const float4* h4c = (const float4*)hf;

  for (int t = 0; t <= fi; ++t) {
    const int p = t & 1;

    // issue prefetch of step t+1 early (hides under the matvec)
    float vnext = 0.f; int fnext = 0;
    const int tn = (t < fi) ? (t + 1) : fi;
    if (tid < 32)       vnext = Xb[tn * C_CH + 33 + tid];
    else if (tid == 32) vnext = Xb[tn * C_CH];
    else if (tid == 33) fnext = (int)anyv[tn];
    else if (tid == 34) fnext = (int)obs[(size_t)b * T_SZ + tn];

    const int fa = flagA[p];
    const int fo = flagO[p];

    if (fa) {
      if (fo) {
        // ---- full GRU step ----
        if (isLo) {
          const float4* xp4 = (const float4*)xs[p];
          float4 xv = xp4[0];
          float a0 = fmaf(w4[0].x, xv.x + dt, bi);
          float a1 = w4[0].y * xv.y;
          float a2 = w4[0].z * xv.z;
          float a3 = w4[0].w * xv.w;
          #pragma unroll
          for (int q = 1; q < 8; ++q) {
            float4 v = xp4[q];
            a0 = fmaf(w4[q].x, v.x, a0);
            a1 = fmaf(w4[q].y, v.y, a1);
            a2 = fmaf(w4[q].z, v.z, a2);
            a3 = fmaf(w4[q].w, v.w, a3);
          }
          float g0 = bhlo, g1 = 0.f, g2 = 0.f, g3 = 0.f;
          #pragma unroll
          for (int q = 0; q < 16; ++q) {
            float4 hv = h4c[q];
            g0 = fmaf(w4[8 + q].x, hv.x, g0);
            g1 = fmaf(w4[8 + q].y, hv.y, g1);
            g2 = fmaf(w4[8 + q].z, hv.z, g2);
            g3 = fmaf(w4[8 + q].w, hv.w, g3);
          }
          plo[row] = make_float2((a0 + a1) + (a2 + a3), (g0 + g1) + (g2 + g3));
        } else if (isHi) {
          float g0 = 0.f, g1 = 0.f, g2 = 0.f, g3 = 0.f;
          #pragma unroll
          for (int q = 0; q < 24; ++q) {
            float4 hv = h4c[16 + q];
            g0 = fmaf(w4[q].x, hv.x, g0);
            g1 = fmaf(w4[q].y, hv.y, g1);
            g2 = fmaf(w4[q].z, hv.z, g2);
            g3 = fmaf(w4[q].w, hv.w, g3);
          }
          phi[row] = (g0 + g1) + (g2 + g3);
        }
        __syncthreads();   // partials visible; all h reads done
        if (tid < HID) {
          float2 pr = plo[tid];            float hr = phi[tid];
          float2 pz = plo[HID + tid];      float hz = phi[HID + tid];
          float2 pn = plo[2 * HID + tid];  float hn = phi[2 * HID + tid];
          float r = sigm_f(pr.x + pr.y + hr);
          float z = sigm_f(pz.x + pz.y + hz);
          float n = tanh_f(fmaf(r, pn.y + hn, pn.x));
          float ho = hf[tid];
          hf[tid] = fmaf(z, ho - n, n);    // (1-z)*n + z*h
        }
      } else {
        // dt-only step (block-uniform, redundantly computed)
        dt += xd0f[p] - times_lds[(t == 0) ? 0 : (t - 1)];
      }
    }
    // publish prefetched step t+1, then barrier
    if (tid < 32)       xs[p ^ 1][tid] = vnext;
    else if (tid == 32) xd0f[p ^ 1] = vnext;
    else if (tid == 33) flagA[p ^ 1] = fnext;
    else if (tid == 34) flagO[p ^ 1] = fnext;
    __syncthreads();
  }

  // final linear: out = lin_w @ h + lin_b
  if (tid < OUTD) {
    const float* lw = lin_w + tid * HID;
    float acc = lin_b[tid];
    #pragma unroll
    for (int k = 0; k < HID; ++k) acc = fmaf(lw[k], hf[k], acc);
    out[(size_t)b * OUTD + tid] = acc;
  }
}

extern "C" void kernel_launch(void* const* d_in, const int* in_sizes, int n_in,
                              void* d_out, int out_size, void* d_ws, size_t ws_size,
                              hipStream_t stream) {
  const float* times = (const float*)d_in[0];
  const float* X     = (const float*)d_in[1];
  const int*   fidx  = (const int*)d_in[2];
  const float* w_ih  = (const float*)d_in[3];
  const float* w_hh  = (const float*)d_in[4];
  const float* b_ih  = (const float*)d_in[5];
  const float* b_hh  = (const float*)d_in[6];
  const float* lin_w = (const float*)d_in[7];
  const float* lin_b = (const float*)d_in[8];
  float* outp = (float*)d_out;

  unsigned char* obs = (unsigned char*)d_ws;
  unsigned* anyv = (unsigned*)((char*)d_ws + (size_t)B_SZ * T_SZ);

  k_zero<<<1, 512, 0, stream>>>(anyv);
  k_obs<<<B_SZ, 256, 0, stream>>>(X, obs, anyv);
  k_scan<<<B_SZ, 1024, 0, stream>>>(times, X, fidx, w_ih, w_hh, b_ih, b_hh,
                                    lin_w, lin_b, obs, anyv, outp);
}